// Round 8
// baseline (1529.033 us; speedup 1.0000x reference)
//
#include <hip/hip_runtime.h>

#define N_NODES 100000
#define N_EDGES 1600000
#define F_IN 32
#define H 128
#define H3 384
#define L_LAYERS 4
#define G_GRAPHS 64
#define NH (N_NODES * H)
#define SCAN_BS 1024
#define NBLK ((N_NODES + SCAN_BS - 1) / SCAN_BS)

typedef short bfrag __attribute__((ext_vector_type(8)));   // 8 bf16 = 4 VGPR
typedef float facc __attribute__((ext_vector_type(4)));    // 4 fp32 acc
typedef unsigned short u16x8 __attribute__((ext_vector_type(8)));

__device__ __forceinline__ float sigmoidf_(float x) { return 1.0f / (1.0f + __expf(-x)); }
__device__ __forceinline__ float bf2f(unsigned int u) { return __uint_as_float(u << 16); }
__device__ __forceinline__ unsigned short f2bf(float f) {
    unsigned int b = __float_as_uint(f);
    return (unsigned short)((b + 0x7FFF + ((b >> 16) & 1)) >> 16);
}
__device__ __forceinline__ facc mfma16(bfrag a, bfrag b, facc c) {
    return __builtin_amdgcn_mfma_f32_16x16x32_bf16(a, b, c, 0, 0, 0);
}

// ---------------- prep: W0T[32][128] = W0[j][k] transposed ----------------
__global__ __launch_bounds__(256) void k_prepw0(const float* __restrict__ W0,
                                                float* __restrict__ W0T) {
    int tid = blockIdx.x * 256 + threadIdx.x;  // [0, 4096)
    int k = tid >> 7, j = tid & 127;
    W0T[tid] = W0[j * F_IN + k];
}

// ---------------- embed ----------------
__global__ __launch_bounds__(256) void k_embed(const float* __restrict__ x,
                                               const float* __restrict__ W0T,
                                               unsigned short* __restrict__ hH,
                                               unsigned short* __restrict__ hL,
                                               float* __restrict__ out_embed) {
    __shared__ float w0s[32][128];
    __shared__ float xsT[32][64];
    const int t = threadIdx.x;
    const int nb = blockIdx.x * 64;
    {
        float4* d = (float4*)&w0s[0][0];
        const float4* s = (const float4*)W0T;
#pragma unroll
        for (int i = 0; i < 4; ++i) d[t + 256 * i] = s[t + 256 * i];
    }
    {
        int n_l = t >> 2, k0 = (t & 3) * 8;
        int n = nb + n_l;
        float4 a = make_float4(0.f, 0.f, 0.f, 0.f), b = a;
        if (n < N_NODES) {
            a = *(const float4*)&x[(size_t)n * F_IN + k0];
            b = *(const float4*)&x[(size_t)n * F_IN + k0 + 4];
        }
        xsT[k0 + 0][n_l] = a.x; xsT[k0 + 1][n_l] = a.y;
        xsT[k0 + 2][n_l] = a.z; xsT[k0 + 3][n_l] = a.w;
        xsT[k0 + 4][n_l] = b.x; xsT[k0 + 5][n_l] = b.y;
        xsT[k0 + 6][n_l] = b.z; xsT[k0 + 7][n_l] = b.w;
    }
    __syncthreads();
    const int n0 = (t >> 5) * 8;
    const int j0 = (t & 31) * 4;
    float4 acc[8];
#pragma unroll
    for (int i = 0; i < 8; ++i) acc[i] = make_float4(0.f, 0.f, 0.f, 0.f);
#pragma unroll 8
    for (int k = 0; k < 32; ++k) {
        float4 w = *(const float4*)&w0s[k][j0];
        float4 va = *(const float4*)&xsT[k][n0];
        float4 vb = *(const float4*)&xsT[k][n0 + 4];
        float xv[8] = {va.x, va.y, va.z, va.w, vb.x, vb.y, vb.z, vb.w};
#pragma unroll
        for (int i = 0; i < 8; ++i) {
            acc[i].x = fmaf(xv[i], w.x, acc[i].x);
            acc[i].y = fmaf(xv[i], w.y, acc[i].y);
            acc[i].z = fmaf(xv[i], w.z, acc[i].z);
            acc[i].w = fmaf(xv[i], w.w, acc[i].w);
        }
    }
#pragma unroll
    for (int i = 0; i < 8; ++i) {
        int n = nb + n0 + i;
        if (n < N_NODES) {
            float4 v;
            v.x = sigmoidf_(acc[i].x); v.y = sigmoidf_(acc[i].y);
            v.z = sigmoidf_(acc[i].z); v.w = sigmoidf_(acc[i].w);
            *(float4*)&out_embed[(size_t)n * H + j0] = v;
            unsigned short h0 = f2bf(v.x), h1 = f2bf(v.y), h2 = f2bf(v.z), h3 = f2bf(v.w);
            unsigned short l0 = f2bf(v.x - bf2f(h0)), l1 = f2bf(v.y - bf2f(h1));
            unsigned short l2 = f2bf(v.z - bf2f(h2)), l3 = f2bf(v.w - bf2f(h3));
            uint2 ph, pl;
            ph.x = (unsigned int)h0 | ((unsigned int)h1 << 16);
            ph.y = (unsigned int)h2 | ((unsigned int)h3 << 16);
            pl.x = (unsigned int)l0 | ((unsigned int)l1 << 16);
            pl.y = (unsigned int)l2 | ((unsigned int)l3 << 16);
            *(uint2*)&hH[(size_t)n * H + j0] = ph;
            *(uint2*)&hL[(size_t)n * H + j0] = pl;
        }
    }
}

// ---------------- CSR build ----------------
__global__ __launch_bounds__(256) void k_hist(const int* __restrict__ ei, int* __restrict__ deg) {
    int e = blockIdx.x * 256 + threadIdx.x;
    if (e >= N_EDGES) return;
    atomicAdd(&deg[ei[N_EDGES + e]], 1);
}

__global__ __launch_bounds__(256) void k_blocksum(const int* __restrict__ deg, int* __restrict__ bsum) {
    int b = blockIdx.x, t = threadIdx.x;
    int base = b * SCAN_BS + t * 4;
    int s = 0;
#pragma unroll
    for (int i = 0; i < 4; ++i) {
        int idx = base + i;
        if (idx < N_NODES) s += deg[idx];
    }
#pragma unroll
    for (int off = 1; off < 64; off <<= 1) s += __shfl_xor(s, off, 64);
    __shared__ int wtot[4];
    if ((t & 63) == 0) wtot[t >> 6] = s;
    __syncthreads();
    if (t == 0) bsum[b] = wtot[0] + wtot[1] + wtot[2] + wtot[3];
}

__global__ void k_topscan(const int* __restrict__ bsum, int* __restrict__ boff) {
    if (threadIdx.x == 0 && blockIdx.x == 0) {
        int acc = 0;
        for (int i = 0; i < NBLK; ++i) { boff[i] = acc; acc += bsum[i]; }
    }
}

__global__ __launch_bounds__(256) void k_scanwrite(const int* __restrict__ deg,
                                                   const int* __restrict__ boff,
                                                   int* __restrict__ offs,
                                                   int* __restrict__ cursor) {
    int b = blockIdx.x, t = threadIdx.x;
    int base = b * SCAN_BS + t * 4;
    int v[4];
    int s = 0;
#pragma unroll
    for (int i = 0; i < 4; ++i) {
        int idx = base + i;
        v[i] = (idx < N_NODES) ? deg[idx] : 0;
        s += v[i];
    }
    int lane = t & 63, w = t >> 6;
    int inc = s;
#pragma unroll
    for (int off = 1; off < 64; off <<= 1) {
        int u = __shfl_up(inc, off, 64);
        if (lane >= off) inc += u;
    }
    __shared__ int wtot[4];
    if (lane == 63) wtot[w] = inc;
    __syncthreads();
    int wpre = 0;
#pragma unroll
    for (int i = 0; i < 4; ++i)
        if (i < w) wpre += wtot[i];
    int run = inc - s + wpre + boff[b];
#pragma unroll
    for (int i = 0; i < 4; ++i) {
        int idx = base + i;
        if (idx < N_NODES) { offs[idx] = run; cursor[idx] = run; run += v[i]; }
    }
    if (b == 0 && t == 0) offs[N_NODES] = N_EDGES;
}

__global__ __launch_bounds__(256) void k_scatter(const int* __restrict__ ei,
                                                 int* __restrict__ cursor,
                                                 int* __restrict__ csr) {
    int e = blockIdx.x * 256 + threadIdx.x;
    if (e >= N_EDGES) return;
    int d = ei[N_EDGES + e];
    int pos = atomicAdd(&cursor[d], 1);
    csr[pos] = ei[e];
}

// ---------------- fold: F[l][k][c] = sum_j conv_w[l][k][j] * w_ih[c][j]  (c<384) --------
// One block per (l,k); 384 threads, thread t -> col c=t.
__global__ __launch_bounds__(384) void k_fold(const float* __restrict__ conv_w,
                                              const float* __restrict__ w_ih,
                                              float* __restrict__ F) {
    __shared__ float wk[128];
    const int l = blockIdx.x >> 7, k = blockIdx.x & 127;
    const int t = threadIdx.x;
    if (t < 32)
        *(float4*)&wk[t * 4] = *(const float4*)&conv_w[((size_t)l * 128 + k) * 128 + t * 4];
    __syncthreads();
    float acc = 0.f;
    const float* wr = &w_ih[(size_t)t * 128];
#pragma unroll 8
    for (int j = 0; j < 128; j += 4) {
        float4 a = *(const float4*)&wr[j];
        acc += a.x * wk[j] + a.y * wk[j + 1] + a.z * wk[j + 2] + a.w * wk[j + 3];
    }
    F[((size_t)l * 128 + k) * 384 + t] = acc;
}

// ---------------- prep: per-layer gate weights [256][512] fragment-major split bf16 ------
// k<128 rows come from folded F (conv @ w_ih^T); k>=128 from w_hh. Layout as before.
__global__ __launch_bounds__(256) void k_prepw(const float* __restrict__ F,
                                               const float* __restrict__ w_hh,
                                               unsigned short* __restrict__ WfH,
                                               unsigned short* __restrict__ WfL) {
    int tid = blockIdx.x * 256 + threadIdx.x;  // [0, L*16384)
    int lyr = tid >> 14;
    int r = tid & 16383;
    int kc = r >> 11;
    int ntg = (r >> 6) & 31;
    int l = r & 63;
    int c = ntg * 16 + (l & 15);
    int g = c >> 7;
    int jg = c & 127;
#pragma unroll
    for (int j = 0; j < 8; ++j) {
        int k = kc * 32 + ((l >> 4) << 3) + j;
        float val;
        if (k < 128) {
            val = (c < 384) ? F[((size_t)lyr * 128 + k) * 384 + c] : 0.f;
        } else {
            int k2 = k - 128;
            if (g == 2) val = 0.f;
            else val = w_hh[((g == 3 ? 256 : g * 128) + jg) * 128 + k2];
        }
        unsigned short hi = f2bf(val);
        WfH[(size_t)tid * 8 + j] = hi;
        WfL[(size_t)tid * 8 + j] = f2bf(val - bf2f(hi));
    }
}

// ---------------- aggregate: hagg[n] = sum_{in-edges} h[src]; emit split bf16 ----------
__global__ __launch_bounds__(256) void k_agg(const int* __restrict__ offs,
                                             const int* __restrict__ csr,
                                             const unsigned short* __restrict__ hH,
                                             const unsigned short* __restrict__ hL,
                                             unsigned short* __restrict__ aggH,
                                             unsigned short* __restrict__ aggL) {
    int t = threadIdx.x;
    int n = blockIdx.x * 4 + (t >> 6);
    int lane = t & 63;
    int beg = offs[n], end = offs[n + 1];
    float2 acc = make_float2(0.f, 0.f);
    for (int i = beg; i < end; ++i) {
        int s0 = csr[i];
        unsigned int uh = *(const unsigned int*)&hH[(size_t)s0 * H + lane * 2];
        unsigned int ul = *(const unsigned int*)&hL[(size_t)s0 * H + lane * 2];
        acc.x += bf2f(uh & 0xffff) + bf2f(ul & 0xffff);
        acc.y += bf2f(uh >> 16) + bf2f(ul >> 16);
    }
    unsigned short hx = f2bf(acc.x);
    unsigned short lx = f2bf(acc.x - bf2f(hx));
    unsigned short hy = f2bf(acc.y);
    unsigned short ly = f2bf(acc.y - bf2f(hy));
    *(unsigned int*)&aggH[(size_t)n * H + lane * 2] = (unsigned int)hx | ((unsigned int)hy << 16);
    *(unsigned int*)&aggL[(size_t)n * H + lane * 2] = (unsigned int)lx | ((unsigned int)ly << 16);
}

// ---------------- fused MFMA gates GEMM + in-register GRU epilogue (64 rows/block) -------
// block: 64 rows x 512 cols; 4 waves; wave wv owns col-slice wv*32 of ALL 4 gates, 4 mtiles.
// 96 MFMA per B-load-pair per kc per wave; 2 barriers per kc for 2x the work of R7.
__global__ __launch_bounds__(256, 2) void k_ggru(const unsigned short* __restrict__ aggH,
                                                 const unsigned short* __restrict__ aggL,
                                                 unsigned short* __restrict__ hH,
                                                 unsigned short* __restrict__ hL,
                                                 const unsigned short* __restrict__ WfH,
                                                 const unsigned short* __restrict__ WfL,
                                                 const float* __restrict__ b_ih,
                                                 const float* __restrict__ b_hh) {
    __shared__ short Ast[2][4][64][8];   // [hi/lo][mtile][lane][8] = 8 KB
    const int t = threadIdx.x;
    const int wv = t >> 6, l = t & 63;
    const int nb = blockIdx.x * 64;

    facc acc[4][4][2];  // [gate][mtile][nt] = 32 facc = 128 VGPR
#pragma unroll
    for (int g = 0; g < 4; ++g)
#pragma unroll
        for (int mt = 0; mt < 4; ++mt)
#pragma unroll
            for (int nt = 0; nt < 2; ++nt) acc[g][mt][nt] = (facc)(0.f);

    const int jb = wv * 32 + (l & 15);
    float brs[2], bzs[2], bis[2], bns[2];
#pragma unroll
    for (int nt = 0; nt < 2; ++nt) {
        int c = jb + nt * 16;
        brs[nt] = b_ih[c] + b_hh[c];
        bzs[nt] = b_ih[128 + c] + b_hh[128 + c];
        bis[nt] = b_ih[256 + c];
        bns[nt] = b_hh[256 + c];
    }

    // staging: wave wv stages part = wv>>1, mtiles mt0, mt0+1
    const int part = wv >> 1;
    const int mt0 = (wv & 1) * 2;
    int srow0 = nb + mt0 * 16 + (l & 15);
    int srow1 = srow0 + 16;
    if (srow0 >= N_NODES) srow0 = N_NODES - 1;   // clamp (outputs guarded)
    if (srow1 >= N_NODES) srow1 = N_NODES - 1;
    const int kb8 = (l >> 4) << 3;
    const unsigned short* aggP = part ? aggL : aggH;
    const unsigned short* hP = part ? hL : hH;

    bfrag sA0 = *(const bfrag*)(aggP + (size_t)srow0 * H + kb8);
    bfrag sA1 = *(const bfrag*)(aggP + (size_t)srow1 * H + kb8);
    for (int kc = 0; kc < 8; ++kc) {
        __syncthreads();
        *(bfrag*)&Ast[part][mt0][l][0] = sA0;
        *(bfrag*)&Ast[part][mt0 + 1][l][0] = sA1;
        if (kc < 7) {
            int kn = kc + 1;
            const unsigned short* base = (kn < 4) ? aggP : hP;
            int off = ((kn & 3) << 5) + kb8;
            sA0 = *(const bfrag*)(base + (size_t)srow0 * H + off);
            sA1 = *(const bfrag*)(base + (size_t)srow1 * H + off);
        }
        __syncthreads();
        bfrag ah[4], al[4];
#pragma unroll
        for (int mt = 0; mt < 4; ++mt) {
            ah[mt] = *(const bfrag*)&Ast[0][mt][l][0];
            al[mt] = *(const bfrag*)&Ast[1][mt][l][0];
        }
        const short* bh = (const short*)WfH + (size_t)((kc * 32 + wv * 2) * 64 + l) * 8;
        const short* bl = (const short*)WfL + (size_t)((kc * 32 + wv * 2) * 64 + l) * 8;
#pragma unroll
        for (int g = 0; g < 4; ++g)
#pragma unroll
            for (int nt = 0; nt < 2; ++nt) {
                bfrag wH = *(const bfrag*)(bh + g * 4096 + nt * 512);
                bfrag wL = *(const bfrag*)(bl + g * 4096 + nt * 512);
#pragma unroll
                for (int mt = 0; mt < 4; ++mt) {
                    acc[g][mt][nt] = mfma16(ah[mt], wH, acc[g][mt][nt]);
                    acc[g][mt][nt] = mfma16(ah[mt], wL, acc[g][mt][nt]);
                    acc[g][mt][nt] = mfma16(al[mt], wH, acc[g][mt][nt]);
                }
            }
    }

    // in-register GRU epilogue
#pragma unroll
    for (int mt = 0; mt < 4; ++mt)
#pragma unroll
        for (int nt = 0; nt < 2; ++nt) {
            int j = jb + nt * 16;
            int r0 = nb + mt * 16 + ((l >> 4) << 2);
#pragma unroll
            for (int reg = 0; reg < 4; ++reg) {
                int row = r0 + reg;
                if (row < N_NODES) {
                    size_t idx = (size_t)row * H + j;
                    float r_ = sigmoidf_(acc[0][mt][nt][reg] + brs[nt]);
                    float z_ = sigmoidf_(acc[1][mt][nt][reg] + bzs[nt]);
                    float ng = tanhf(acc[2][mt][nt][reg] + bis[nt] + r_ * (acc[3][mt][nt][reg] + bns[nt]));
                    float ho = bf2f(hH[idx]) + bf2f(hL[idx]);
                    float hn = (1.f - z_) * ng + z_ * ho;
                    unsigned short hb = f2bf(hn);
                    hH[idx] = hb;
                    hL[idx] = f2bf(hn - bf2f(hb));
                }
            }
        }
}

// ---------------- final linear + relu + LDS-staged per-graph accumulation ----------------
__global__ __launch_bounds__(256) void k_out(const unsigned short* __restrict__ hH,
                                             const unsigned short* __restrict__ hL,
                                             const float* __restrict__ lw,
                                             const float* __restrict__ lb,
                                             const int* __restrict__ batch,
                                             float* __restrict__ unc,
                                             float* __restrict__ gsum,
                                             float* __restrict__ gcnt) {
    __shared__ float sgs[G_GRAPHS];
    __shared__ float sgc[G_GRAPHS];
    const int t = threadIdx.x;
    if (t < G_GRAPHS) { sgs[t] = 0.f; sgc[t] = 0.f; }
    __syncthreads();
    const int lane = t & 63;
    const int grp = t >> 6;
    const float2 wv = *(const float2*)&lw[lane * 2];
    const float lbv = lb[0];
    const int base = blockIdx.x * 64;
#pragma unroll 4
    for (int it = 0; it < 16; ++it) {
        int n = base + it * 4 + grp;
        if (n < N_NODES) {
            unsigned int uh = *(const unsigned int*)&hH[(size_t)n * H + lane * 2];
            unsigned int ul = *(const unsigned int*)&hL[(size_t)n * H + lane * 2];
            float h0 = bf2f(uh & 0xffff) + bf2f(ul & 0xffff);
            float h1 = bf2f(uh >> 16) + bf2f(ul >> 16);
            float v = fmaxf(h0, 0.f) * wv.x + fmaxf(h1, 0.f) * wv.y;
#pragma unroll
            for (int off = 32; off >= 1; off >>= 1) v += __shfl_xor(v, off, 64);
            if (lane == 0) {
                float o = v + lbv;
                unc[n] = o;
                int b = batch[n];
                atomicAdd(&sgs[b], o);
                atomicAdd(&sgc[b], 1.0f);
            }
        }
    }
    __syncthreads();
    if (t < G_GRAPHS && sgc[t] != 0.f) {
        atomicAdd(&gsum[t], sgs[t]);
        atomicAdd(&gcnt[t], sgc[t]);
    }
}

__global__ __launch_bounds__(256) void k_corr(const float* __restrict__ unc,
                                              const int* __restrict__ batch,
                                              const float* __restrict__ gsum,
                                              const float* __restrict__ gcnt,
                                              float* __restrict__ corr) {
    int n = blockIdx.x * 256 + threadIdx.x;
    if (n >= N_NODES) return;
    int b = batch[n];
    float mean = gsum[b] / fmaxf(gcnt[b], 1.0f);
    corr[n] = unc[n] - mean;
}

extern "C" void kernel_launch(void* const* d_in, const int* in_sizes, int n_in,
                              void* d_out, int out_size, void* d_ws, size_t ws_size,
                              hipStream_t stream) {
    const float* x      = (const float*)d_in[0];
    const int*   ei     = (const int*)d_in[1];
    const int*   batch  = (const int*)d_in[2];
    const float* W0     = (const float*)d_in[4];
    const float* conv_w = (const float*)d_in[5];
    const float* w_ih   = (const float*)d_in[6];
    const float* b_ih   = (const float*)d_in[7];
    const float* w_hh   = (const float*)d_in[8];
    const float* b_hh   = (const float*)d_in[9];
    const float* lin1_w = (const float*)d_in[10];
    const float* lin1_b = (const float*)d_in[11];

    float* out = (float*)d_out;
    float* ws  = (float*)d_ws;

    float* gsum = ws;                                // G
    float* gcnt = gsum + G_GRAPHS;                   // G
    float* Wfold = ws + 128;                         // L*128*384 = 196608
    int*   deg    = (int*)(Wfold + 196608);          // N
    int*   offs   = deg + N_NODES;                   // N+1
    int*   cursor = offs + N_NODES + 1;              // N
    int*   bsum   = cursor + N_NODES;                // NBLK
    int*   boff   = bsum + NBLK;                     // NBLK
    int*   csr    = boff + NBLK;                     // E
    // 16B-aligned ushort region (offset 128+196608+1900200 floats = 8387744 B, /16 ok)
    unsigned short* aggH = (unsigned short*)(ws + 128 + 196608 + 1900200);
    unsigned short* aggL = aggH + (size_t)NH;
    unsigned short* hH   = aggL + (size_t)NH;
    unsigned short* hL   = hH + (size_t)NH;
    unsigned short* WfH  = hL + (size_t)NH;          // L * 131072
    unsigned short* WfL  = WfH + (size_t)L_LAYERS * 131072;
    float*          W0T  = (float*)(WfL + (size_t)L_LAYERS * 131072);  // 4096

    float* out_corr  = out;                          // [N]
    float* out_embed = out + N_NODES;                // [N*H]
    float* out_unc   = out + N_NODES + (size_t)NH;   // [N]

    hipMemsetAsync(gsum, 0, 2 * G_GRAPHS * sizeof(float), stream);
    hipMemsetAsync(deg, 0, N_NODES * sizeof(int), stream);

    k_fold<<<L_LAYERS * 128, 384, 0, stream>>>(conv_w, w_ih, Wfold);
    k_prepw<<<L_LAYERS * 64, 256, 0, stream>>>(Wfold, w_hh, WfH, WfL);
    k_prepw0<<<16, 256, 0, stream>>>(W0, W0T);
    k_embed<<<(N_NODES + 63) / 64, 256, 0, stream>>>(x, W0T, hH, hL, out_embed);

    k_hist<<<(N_EDGES + 255) / 256, 256, 0, stream>>>(ei, deg);
    k_blocksum<<<NBLK, 256, 0, stream>>>(deg, bsum);
    k_topscan<<<1, 64, 0, stream>>>(bsum, boff);
    k_scanwrite<<<NBLK, 256, 0, stream>>>(deg, boff, offs, cursor);
    k_scatter<<<(N_EDGES + 255) / 256, 256, 0, stream>>>(ei, cursor, csr);

    for (int l = 0; l < L_LAYERS; ++l) {
        k_agg<<<N_NODES / 4, 256, 0, stream>>>(offs, csr, hH, hL, aggH, aggL);
        k_ggru<<<(N_NODES + 63) / 64, 256, 0, stream>>>(aggH, aggL, hH, hL,
                                                        WfH + (size_t)l * 131072,
                                                        WfL + (size_t)l * 131072, b_ih, b_hh);
    }

    k_out<<<(N_NODES + 63) / 64, 256, 0, stream>>>(hH, hL, lin1_w, lin1_b, batch, out_unc, gsum, gcnt);
    k_corr<<<(N_NODES + 255) / 256, 256, 0, stream>>>(out_unc, batch, gsum, gcnt, out_corr);
}

// Round 9
// 1449.311 us; speedup vs baseline: 1.0550x; 1.0550x over previous
//
#include <hip/hip_runtime.h>

#define N_NODES 100000
#define N_EDGES 1600000
#define F_IN 32
#define H 128
#define H3 384
#define L_LAYERS 4
#define G_GRAPHS 64
#define NH (N_NODES * H)
#define SCAN_BS 1024
#define NBLK ((N_NODES + SCAN_BS - 1) / SCAN_BS)

typedef short bfrag __attribute__((ext_vector_type(8)));   // 8 bf16 = 4 VGPR
typedef float facc __attribute__((ext_vector_type(4)));    // 4 fp32 acc

__device__ __forceinline__ float sigmoidf_(float x) { return 1.0f / (1.0f + __expf(-x)); }
__device__ __forceinline__ float bf2f(unsigned int u) { return __uint_as_float(u << 16); }
__device__ __forceinline__ unsigned short f2bf(float f) {
    unsigned int b = __float_as_uint(f);
    return (unsigned short)((b + 0x7FFF + ((b >> 16) & 1)) >> 16);
}
// packed split-bf16: p = hi | (lo<<16); value = bf2f(hi) + bf2f(lo)
__device__ __forceinline__ float unpack2(unsigned int p) {
    return __uint_as_float(p << 16) + __uint_as_float(p & 0xffff0000u);
}
__device__ __forceinline__ unsigned int pack2(float v) {
    unsigned short hi = f2bf(v);
    unsigned short lo = f2bf(v - bf2f(hi));
    return (unsigned int)hi | ((unsigned int)lo << 16);
}
__device__ __forceinline__ facc mfma16(bfrag a, bfrag b, facc c) {
    return __builtin_amdgcn_mfma_f32_16x16x32_bf16(a, b, c, 0, 0, 0);
}

// ---------------- prep: W0T[32][128] = W0[j][k] transposed ----------------
__global__ __launch_bounds__(256) void k_prepw0(const float* __restrict__ W0,
                                                float* __restrict__ W0T) {
    int tid = blockIdx.x * 256 + threadIdx.x;  // [0, 4096)
    int k = tid >> 7, j = tid & 127;
    W0T[tid] = W0[j * F_IN + k];
}

// ---------------- embed ----------------
__global__ __launch_bounds__(256) void k_embed(const float* __restrict__ x,
                                               const float* __restrict__ W0T,
                                               unsigned int* __restrict__ hPk,
                                               float* __restrict__ out_embed) {
    __shared__ float w0s[32][128];
    __shared__ float xsT[32][64];
    const int t = threadIdx.x;
    const int nb = blockIdx.x * 64;
    {
        float4* d = (float4*)&w0s[0][0];
        const float4* s = (const float4*)W0T;
#pragma unroll
        for (int i = 0; i < 4; ++i) d[t + 256 * i] = s[t + 256 * i];
    }
    {
        int n_l = t >> 2, k0 = (t & 3) * 8;
        int n = nb + n_l;
        float4 a = make_float4(0.f, 0.f, 0.f, 0.f), b = a;
        if (n < N_NODES) {
            a = *(const float4*)&x[(size_t)n * F_IN + k0];
            b = *(const float4*)&x[(size_t)n * F_IN + k0 + 4];
        }
        xsT[k0 + 0][n_l] = a.x; xsT[k0 + 1][n_l] = a.y;
        xsT[k0 + 2][n_l] = a.z; xsT[k0 + 3][n_l] = a.w;
        xsT[k0 + 4][n_l] = b.x; xsT[k0 + 5][n_l] = b.y;
        xsT[k0 + 6][n_l] = b.z; xsT[k0 + 7][n_l] = b.w;
    }
    __syncthreads();
    const int n0 = (t >> 5) * 8;
    const int j0 = (t & 31) * 4;
    float4 acc[8];
#pragma unroll
    for (int i = 0; i < 8; ++i) acc[i] = make_float4(0.f, 0.f, 0.f, 0.f);
#pragma unroll 8
    for (int k = 0; k < 32; ++k) {
        float4 w = *(const float4*)&w0s[k][j0];
        float4 va = *(const float4*)&xsT[k][n0];
        float4 vb = *(const float4*)&xsT[k][n0 + 4];
        float xv[8] = {va.x, va.y, va.z, va.w, vb.x, vb.y, vb.z, vb.w};
#pragma unroll
        for (int i = 0; i < 8; ++i) {
            acc[i].x = fmaf(xv[i], w.x, acc[i].x);
            acc[i].y = fmaf(xv[i], w.y, acc[i].y);
            acc[i].z = fmaf(xv[i], w.z, acc[i].z);
            acc[i].w = fmaf(xv[i], w.w, acc[i].w);
        }
    }
#pragma unroll
    for (int i = 0; i < 8; ++i) {
        int n = nb + n0 + i;
        if (n < N_NODES) {
            float4 v;
            v.x = sigmoidf_(acc[i].x); v.y = sigmoidf_(acc[i].y);
            v.z = sigmoidf_(acc[i].z); v.w = sigmoidf_(acc[i].w);
            *(float4*)&out_embed[(size_t)n * H + j0] = v;
            uint4 pk;
            pk.x = pack2(v.x); pk.y = pack2(v.y);
            pk.z = pack2(v.z); pk.w = pack2(v.w);
            *(uint4*)&hPk[(size_t)n * H + j0] = pk;
        }
    }
}

// ---------------- CSR build ----------------
__global__ __launch_bounds__(256) void k_hist(const int* __restrict__ ei, int* __restrict__ deg) {
    int e = blockIdx.x * 256 + threadIdx.x;
    if (e >= N_EDGES) return;
    atomicAdd(&deg[ei[N_EDGES + e]], 1);
}

__global__ __launch_bounds__(256) void k_blocksum(const int* __restrict__ deg, int* __restrict__ bsum) {
    int b = blockIdx.x, t = threadIdx.x;
    int base = b * SCAN_BS + t * 4;
    int s = 0;
#pragma unroll
    for (int i = 0; i < 4; ++i) {
        int idx = base + i;
        if (idx < N_NODES) s += deg[idx];
    }
#pragma unroll
    for (int off = 1; off < 64; off <<= 1) s += __shfl_xor(s, off, 64);
    __shared__ int wtot[4];
    if ((t & 63) == 0) wtot[t >> 6] = s;
    __syncthreads();
    if (t == 0) bsum[b] = wtot[0] + wtot[1] + wtot[2] + wtot[3];
}

__global__ void k_topscan(const int* __restrict__ bsum, int* __restrict__ boff) {
    if (threadIdx.x == 0 && blockIdx.x == 0) {
        int acc = 0;
        for (int i = 0; i < NBLK; ++i) { boff[i] = acc; acc += bsum[i]; }
    }
}

__global__ __launch_bounds__(256) void k_scanwrite(const int* __restrict__ deg,
                                                   const int* __restrict__ boff,
                                                   int* __restrict__ offs,
                                                   int* __restrict__ cursor) {
    int b = blockIdx.x, t = threadIdx.x;
    int base = b * SCAN_BS + t * 4;
    int v[4];
    int s = 0;
#pragma unroll
    for (int i = 0; i < 4; ++i) {
        int idx = base + i;
        v[i] = (idx < N_NODES) ? deg[idx] : 0;
        s += v[i];
    }
    int lane = t & 63, w = t >> 6;
    int inc = s;
#pragma unroll
    for (int off = 1; off < 64; off <<= 1) {
        int u = __shfl_up(inc, off, 64);
        if (lane >= off) inc += u;
    }
    __shared__ int wtot[4];
    if (lane == 63) wtot[w] = inc;
    __syncthreads();
    int wpre = 0;
#pragma unroll
    for (int i = 0; i < 4; ++i)
        if (i < w) wpre += wtot[i];
    int run = inc - s + wpre + boff[b];
#pragma unroll
    for (int i = 0; i < 4; ++i) {
        int idx = base + i;
        if (idx < N_NODES) { offs[idx] = run; cursor[idx] = run; run += v[i]; }
    }
    if (b == 0 && t == 0) offs[N_NODES] = N_EDGES;
}

__global__ __launch_bounds__(256) void k_scatter(const int* __restrict__ ei,
                                                 int* __restrict__ cursor,
                                                 int* __restrict__ csr) {
    int e = blockIdx.x * 256 + threadIdx.x;
    if (e >= N_EDGES) return;
    int d = ei[N_EDGES + e];
    int pos = atomicAdd(&cursor[d], 1);
    csr[pos] = ei[e];
}

// ---------------- fold: F[l][k][c] = sum_j conv_w[l][k][j] * w_ih[c][j]  (c<384) --------
__global__ __launch_bounds__(384) void k_fold(const float* __restrict__ conv_w,
                                              const float* __restrict__ w_ih,
                                              float* __restrict__ F) {
    __shared__ float wk[128];
    const int l = blockIdx.x >> 7, k = blockIdx.x & 127;
    const int t = threadIdx.x;
    if (t < 32)
        *(float4*)&wk[t * 4] = *(const float4*)&conv_w[((size_t)l * 128 + k) * 128 + t * 4];
    __syncthreads();
    float acc = 0.f;
    const float* wr = &w_ih[(size_t)t * 128];
#pragma unroll 8
    for (int j = 0; j < 128; j += 4) {
        float4 a = *(const float4*)&wr[j];
        acc += a.x * wk[j] + a.y * wk[j + 1] + a.z * wk[j + 2] + a.w * wk[j + 3];
    }
    F[((size_t)l * 128 + k) * 384 + t] = acc;
}

// ---------------- prep: per-layer gate weights [256][512] fragment-major split bf16 ------
__global__ __launch_bounds__(256) void k_prepw(const float* __restrict__ F,
                                               const float* __restrict__ w_hh,
                                               unsigned short* __restrict__ WfH,
                                               unsigned short* __restrict__ WfL) {
    int tid = blockIdx.x * 256 + threadIdx.x;  // [0, L*16384)
    int lyr = tid >> 14;
    int r = tid & 16383;
    int kc = r >> 11;
    int ntg = (r >> 6) & 31;
    int l = r & 63;
    int c = ntg * 16 + (l & 15);
    int g = c >> 7;
    int jg = c & 127;
#pragma unroll
    for (int j = 0; j < 8; ++j) {
        int k = kc * 32 + ((l >> 4) << 3) + j;
        float val;
        if (k < 128) {
            val = (c < 384) ? F[((size_t)lyr * 128 + k) * 384 + c] : 0.f;
        } else {
            int k2 = k - 128;
            if (g == 2) val = 0.f;
            else val = w_hh[((g == 3 ? 256 : g * 128) + jg) * 128 + k2];
        }
        unsigned short hi = f2bf(val);
        WfH[(size_t)tid * 8 + j] = hi;
        WfL[(size_t)tid * 8 + j] = f2bf(val - bf2f(hi));
    }
}

// ---------------- aggregate: aggPk[n] = pack(sum_{in-edges} h[src]) ----------
__global__ __launch_bounds__(256) void k_agg(const int* __restrict__ offs,
                                             const int* __restrict__ csr,
                                             const unsigned int* __restrict__ hPk,
                                             unsigned int* __restrict__ aggPk) {
    int t = threadIdx.x;
    int n = blockIdx.x * 4 + (t >> 6);
    int lane = t & 63;
    int beg = offs[n], end = offs[n + 1];
    float2 acc0 = make_float2(0.f, 0.f), acc1 = acc0;
    int i = beg;
    for (; i + 1 < end; i += 2) {
        int s0 = csr[i], s1 = csr[i + 1];
        uint2 a = *(const uint2*)&hPk[(size_t)s0 * H + lane * 2];
        uint2 b = *(const uint2*)&hPk[(size_t)s1 * H + lane * 2];
        acc0.x += unpack2(a.x); acc0.y += unpack2(a.y);
        acc1.x += unpack2(b.x); acc1.y += unpack2(b.y);
    }
    if (i < end) {
        uint2 a = *(const uint2*)&hPk[(size_t)csr[i] * H + lane * 2];
        acc0.x += unpack2(a.x); acc0.y += unpack2(a.y);
    }
    uint2 o;
    o.x = pack2(acc0.x + acc1.x);
    o.y = pack2(acc0.y + acc1.y);
    *(uint2*)&aggPk[(size_t)n * H + lane * 2] = o;
}

// ---------------- fused MFMA gates GEMM + in-register GRU epilogue (64 rows/block) -------
// Wave wv stages mtile wv (both hi/lo parts extracted from packed storage).
__global__ __launch_bounds__(256, 2) void k_ggru(const unsigned int* __restrict__ aggPk,
                                                 unsigned int* __restrict__ hPk,
                                                 const unsigned short* __restrict__ WfH,
                                                 const unsigned short* __restrict__ WfL,
                                                 const float* __restrict__ b_ih,
                                                 const float* __restrict__ b_hh) {
    __shared__ short Ast[2][4][64][8];   // [hi/lo][mtile][lane][8] = 8 KB
    const int t = threadIdx.x;
    const int wv = t >> 6, l = t & 63;
    const int nb = blockIdx.x * 64;

    facc acc[4][4][2];  // [gate][mtile][nt] = 128 VGPR
#pragma unroll
    for (int g = 0; g < 4; ++g)
#pragma unroll
        for (int mt = 0; mt < 4; ++mt)
#pragma unroll
            for (int nt = 0; nt < 2; ++nt) acc[g][mt][nt] = (facc)(0.f);

    const int jb = wv * 32 + (l & 15);
    float brs[2], bzs[2], bis[2], bns[2];
#pragma unroll
    for (int nt = 0; nt < 2; ++nt) {
        int c = jb + nt * 16;
        brs[nt] = b_ih[c] + b_hh[c];
        bzs[nt] = b_ih[128 + c] + b_hh[128 + c];
        bis[nt] = b_ih[256 + c];
        bns[nt] = b_hh[256 + c];
    }

    // staging: wave wv stages mtile wv, both parts from packed storage
    int srow = nb + wv * 16 + (l & 15);
    if (srow >= N_NODES) srow = N_NODES - 1;   // clamp (outputs guarded)
    const int kb8 = (l >> 4) << 3;

    uint4 p0 = *(const uint4*)(aggPk + (size_t)srow * H + kb8);
    uint4 p1 = *(const uint4*)(aggPk + (size_t)srow * H + kb8 + 4);
    for (int kc = 0; kc < 8; ++kc) {
        __syncthreads();
        {
            bfrag hi, lo;
            hi[0] = (short)(p0.x & 0xffff); lo[0] = (short)(p0.x >> 16);
            hi[1] = (short)(p0.y & 0xffff); lo[1] = (short)(p0.y >> 16);
            hi[2] = (short)(p0.z & 0xffff); lo[2] = (short)(p0.z >> 16);
            hi[3] = (short)(p0.w & 0xffff); lo[3] = (short)(p0.w >> 16);
            hi[4] = (short)(p1.x & 0xffff); lo[4] = (short)(p1.x >> 16);
            hi[5] = (short)(p1.y & 0xffff); lo[5] = (short)(p1.y >> 16);
            hi[6] = (short)(p1.z & 0xffff); lo[6] = (short)(p1.z >> 16);
            hi[7] = (short)(p1.w & 0xffff); lo[7] = (short)(p1.w >> 16);
            *(bfrag*)&Ast[0][wv][l][0] = hi;
            *(bfrag*)&Ast[1][wv][l][0] = lo;
        }
        if (kc < 7) {
            int kn = kc + 1;
            const unsigned int* base = (kn < 4) ? aggPk : hPk;
            size_t off = (size_t)srow * H + ((kn & 3) << 5) + kb8;
            p0 = *(const uint4*)(base + off);
            p1 = *(const uint4*)(base + off + 4);
        }
        __syncthreads();
        bfrag ah[4], al[4];
#pragma unroll
        for (int mt = 0; mt < 4; ++mt) {
            ah[mt] = *(const bfrag*)&Ast[0][mt][l][0];
            al[mt] = *(const bfrag*)&Ast[1][mt][l][0];
        }
        const short* bh = (const short*)WfH + (size_t)((kc * 32 + wv * 2) * 64 + l) * 8;
        const short* bl = (const short*)WfL + (size_t)((kc * 32 + wv * 2) * 64 + l) * 8;
#pragma unroll
        for (int g = 0; g < 4; ++g)
#pragma unroll
            for (int nt = 0; nt < 2; ++nt) {
                bfrag wH = *(const bfrag*)(bh + g * 4096 + nt * 512);
                bfrag wL = *(const bfrag*)(bl + g * 4096 + nt * 512);
#pragma unroll
                for (int mt = 0; mt < 4; ++mt) {
                    acc[g][mt][nt] = mfma16(ah[mt], wH, acc[g][mt][nt]);
                    acc[g][mt][nt] = mfma16(ah[mt], wL, acc[g][mt][nt]);
                    acc[g][mt][nt] = mfma16(al[mt], wH, acc[g][mt][nt]);
                }
            }
    }

    // in-register GRU epilogue (packed h read/modify/write, 4B per element)
#pragma unroll
    for (int mt = 0; mt < 4; ++mt)
#pragma unroll
        for (int nt = 0; nt < 2; ++nt) {
            int j = jb + nt * 16;
            int r0 = nb + mt * 16 + ((l >> 4) << 2);
#pragma unroll
            for (int reg = 0; reg < 4; ++reg) {
                int row = r0 + reg;
                if (row < N_NODES) {
                    size_t idx = (size_t)row * H + j;
                    float r_ = sigmoidf_(acc[0][mt][nt][reg] + brs[nt]);
                    float z_ = sigmoidf_(acc[1][mt][nt][reg] + bzs[nt]);
                    float ng = tanhf(acc[2][mt][nt][reg] + bis[nt] + r_ * (acc[3][mt][nt][reg] + bns[nt]));
                    float ho = unpack2(hPk[idx]);
                    float hn = (1.f - z_) * ng + z_ * ho;
                    hPk[idx] = pack2(hn);
                }
            }
        }
}

// ---------------- final linear + relu + LDS-staged per-graph accumulation ----------------
__global__ __launch_bounds__(256) void k_out(const unsigned int* __restrict__ hPk,
                                             const float* __restrict__ lw,
                                             const float* __restrict__ lb,
                                             const int* __restrict__ batch,
                                             float* __restrict__ unc,
                                             float* __restrict__ gsum,
                                             float* __restrict__ gcnt) {
    __shared__ float sgs[G_GRAPHS];
    __shared__ float sgc[G_GRAPHS];
    const int t = threadIdx.x;
    if (t < G_GRAPHS) { sgs[t] = 0.f; sgc[t] = 0.f; }
    __syncthreads();
    const int lane = t & 63;
    const int grp = t >> 6;
    const float2 wv = *(const float2*)&lw[lane * 2];
    const float lbv = lb[0];
    const int base = blockIdx.x * 64;
#pragma unroll 4
    for (int it = 0; it < 16; ++it) {
        int n = base + it * 4 + grp;
        if (n < N_NODES) {
            uint2 u = *(const uint2*)&hPk[(size_t)n * H + lane * 2];
            float h0 = unpack2(u.x);
            float h1 = unpack2(u.y);
            float v = fmaxf(h0, 0.f) * wv.x + fmaxf(h1, 0.f) * wv.y;
#pragma unroll
            for (int off = 32; off >= 1; off >>= 1) v += __shfl_xor(v, off, 64);
            if (lane == 0) {
                float o = v + lbv;
                unc[n] = o;
                int b = batch[n];
                atomicAdd(&sgs[b], o);
                atomicAdd(&sgc[b], 1.0f);
            }
        }
    }
    __syncthreads();
    if (t < G_GRAPHS && sgc[t] != 0.f) {
        atomicAdd(&gsum[t], sgs[t]);
        atomicAdd(&gcnt[t], sgc[t]);
    }
}

__global__ __launch_bounds__(256) void k_corr(const float* __restrict__ unc,
                                              const int* __restrict__ batch,
                                              const float* __restrict__ gsum,
                                              const float* __restrict__ gcnt,
                                              float* __restrict__ corr) {
    int n = blockIdx.x * 256 + threadIdx.x;
    if (n >= N_NODES) return;
    int b = batch[n];
    float mean = gsum[b] / fmaxf(gcnt[b], 1.0f);
    corr[n] = unc[n] - mean;
}

extern "C" void kernel_launch(void* const* d_in, const int* in_sizes, int n_in,
                              void* d_out, int out_size, void* d_ws, size_t ws_size,
                              hipStream_t stream) {
    const float* x      = (const float*)d_in[0];
    const int*   ei     = (const int*)d_in[1];
    const int*   batch  = (const int*)d_in[2];
    const float* W0     = (const float*)d_in[4];
    const float* conv_w = (const float*)d_in[5];
    const float* w_ih   = (const float*)d_in[6];
    const float* b_ih   = (const float*)d_in[7];
    const float* w_hh   = (const float*)d_in[8];
    const float* b_hh   = (const float*)d_in[9];
    const float* lin1_w = (const float*)d_in[10];
    const float* lin1_b = (const float*)d_in[11];

    float* out = (float*)d_out;
    float* ws  = (float*)d_ws;

    float* gsum = ws;                                // G
    float* gcnt = gsum + G_GRAPHS;                   // G
    float* Wfold = ws + 128;                         // L*128*384 = 196608
    int*   deg    = (int*)(Wfold + 196608);          // N
    int*   offs   = deg + N_NODES;                   // N+1
    int*   cursor = offs + N_NODES + 1;              // N
    int*   bsum   = cursor + N_NODES;                // NBLK
    int*   boff   = bsum + NBLK;                     // NBLK
    int*   csr    = boff + NBLK;                     // E
    // 16B-aligned packed region
    unsigned int* aggPk = (unsigned int*)(ws + 128 + 196608 + 1900200);
    unsigned int* hPk   = aggPk + (size_t)NH;
    unsigned short* WfH = (unsigned short*)(hPk + (size_t)NH);   // L * 131072
    unsigned short* WfL = WfH + (size_t)L_LAYERS * 131072;
    float*          W0T = (float*)(WfL + (size_t)L_LAYERS * 131072);  // 4096

    float* out_corr  = out;                          // [N]
    float* out_embed = out + N_NODES;                // [N*H]
    float* out_unc   = out + N_NODES + (size_t)NH;   // [N]

    hipMemsetAsync(gsum, 0, 2 * G_GRAPHS * sizeof(float), stream);
    hipMemsetAsync(deg, 0, N_NODES * sizeof(int), stream);

    k_fold<<<L_LAYERS * 128, 384, 0, stream>>>(conv_w, w_ih, Wfold);
    k_prepw<<<L_LAYERS * 64, 256, 0, stream>>>(Wfold, w_hh, WfH, WfL);
    k_prepw0<<<16, 256, 0, stream>>>(W0, W0T);
    k_embed<<<(N_NODES + 63) / 64, 256, 0, stream>>>(x, W0T, hPk, out_embed);

    k_hist<<<(N_EDGES + 255) / 256, 256, 0, stream>>>(ei, deg);
    k_blocksum<<<NBLK, 256, 0, stream>>>(deg, bsum);
    k_topscan<<<1, 64, 0, stream>>>(bsum, boff);
    k_scanwrite<<<NBLK, 256, 0, stream>>>(deg, boff, offs, cursor);
    k_scatter<<<(N_EDGES + 255) / 256, 256, 0, stream>>>(ei, cursor, csr);

    for (int l = 0; l < L_LAYERS; ++l) {
        k_agg<<<N_NODES / 4, 256, 0, stream>>>(offs, csr, hPk, aggPk);
        k_ggru<<<(N_NODES + 63) / 64, 256, 0, stream>>>(aggPk, hPk,
                                                        WfH + (size_t)l * 131072,
                                                        WfL + (size_t)l * 131072, b_ih, b_hh);
    }

    k_out<<<(N_NODES + 63) / 64, 256, 0, stream>>>(hPk, lin1_w, lin1_b, batch, out_unc, gsum, gcnt);
    k_corr<<<(N_NODES + 255) / 256, 256, 0, stream>>>(out_unc, batch, gsum, gcnt, out_corr);
}